// Round 14
// baseline (161.702 us; speedup 1.0000x reference)
//
#include <hip/hip_runtime.h>
#include <hip/hip_cooperative_groups.h>

// PillarLayer: fused copy + per-pillar xyz center-of-mass + BEV canvas scatter.
//
// R14 = R13 (72.1us) with K1 (canvas zero) fused into the main kernel via a
// single cooperative launch + grid.sync(). Removes one kernel launch and the
// non-overlapped zero burst. Phase B body identical to R13 (16 lanes/pillar,
// 2 NT float4 loads per lane, 12 ds_swizzle per 2KB wave, cacheable stores,
// direct cacheable scatter into L3-resident zeroed lines).
//
// Inputs: d_in[0] pillars f32 (P,32,4); d_in[1] coors int32 (P,4) [b,x,y,z];
//         d_in[2] npoints int32 (P); d_in[3] bs; d_in[4] x_l; d_in[5] y_l.
// Output (concat f32): pillars copy | coors as f32 | npoints as f32 |
//         canvas (bs,3,y_l,x_l) with canvas[b][c][y][x] = center_c or 0.

typedef float vfloat4 __attribute__((ext_vector_type(4)));

__global__ __launch_bounds__(256) void pillar_coop(
    const vfloat4* __restrict__ pillars4,  // P*32 (one float4 per point)
    const int4* __restrict__ coors4,       // P [b,x,y,z]
    const int* __restrict__ npoints,       // P
    const int* __restrict__ xlp,           // scalar x_l
    const int* __restrict__ ylp,           // scalar y_l
    vfloat4* __restrict__ out_pillars4,    // P*32
    float4* __restrict__ out_coors4,       // P
    float* __restrict__ out_np,            // P
    float4* __restrict__ canvas4,          // canvas as float4 (16B-aligned)
    long n4,                               // canvas float4 count
    int P)
{
    // ---- Phase A: zero the canvas (grid-stride, cacheable -> L3-resident).
    {
        const long stride = (long)gridDim.x * blockDim.x;
        const float4 z = make_float4(0.f, 0.f, 0.f, 0.f);
        for (long i = (long)blockIdx.x * blockDim.x + threadIdx.x; i < n4; i += stride)
            canvas4[i] = z;
    }
    cooperative_groups::this_grid().sync();

    // ---- Phase B: copy + reduce + scatter (R13 body, grid-stride chunks).
    float* __restrict__ canvas = (float*)canvas4;
    const int tid = threadIdx.x;
    const int g   = tid >> 4;                  // pillar group within block (0..15)
    const int r   = tid & 15;                  // lane within pillar
    const int x_l = *xlp;
    const int y_l = *ylp;
    const long cs = (long)y_l * (long)x_l;     // canvas plane stride
    const int nchunks = (P + 15) >> 4;         // 16 pillars per chunk

    for (int chunk = blockIdx.x; chunk < nchunks; chunk += gridDim.x) {
        const int p = chunk * 16 + g;
        if (p >= P) continue;

        const long b0 = (long)p * 32;          // pillar's first float4

        // NT loads (read-once; keep L3 for the zeroed canvas); per instruction
        // a wave covers 4 x 256B full-line segments.
        const vfloat4 v0 = __builtin_nontemporal_load(&pillars4[b0 + r]);
        const vfloat4 v1 = __builtin_nontemporal_load(&pillars4[b0 + r + 16]);
        out_pillars4[b0 + r]      = v0;        // cacheable writeback stores
        out_pillars4[b0 + r + 16] = v1;

        // Local pair-add then 4-step butterfly within the 16-lane group
        // (xor masks < 16 stay inside the group on wave64).
        float sx = v0.x + v1.x, sy = v0.y + v1.y, sz = v0.z + v1.z;
        #pragma unroll
        for (int m = 8; m >= 1; m >>= 1) {
            sx += __shfl_xor(sx, m);
            sy += __shfl_xor(sy, m);
            sz += __shfl_xor(sz, m);
        }

        if (r < 3) {
            const int4 c   = coors4[p];        // broadcast per 16-lane group
            const int npts = npoints[p];
            const float s  = (r == 0) ? sx : (r == 1) ? sy : sz;
            const float val = s / (float)npts;

            const long base = (long)c.x * 3l * cs + (long)c.z * (long)x_l + (long)c.y;
            canvas[base + (long)r * cs] = val; // plane r via lane r

            if (r == 0) {
                out_coors4[p] = make_float4((float)c.x, (float)c.y, (float)c.z, (float)c.w);
                out_np[p]     = (float)npts;
            }
        }
    }
}

extern "C" void kernel_launch(void* const* d_in, const int* in_sizes, int n_in,
                              void* d_out, int out_size, void* d_ws, size_t ws_size,
                              hipStream_t stream) {
    const vfloat4* pillars4 = (const vfloat4*)d_in[0];
    const int4* coors4      = (const int4*)d_in[1];
    const int* npoints      = (const int*)d_in[2];
    const int* xlp = (const int*)d_in[4];
    const int* ylp = (const int*)d_in[5];

    const int n_pillars = in_sizes[0];   // P*128
    const int n_coors   = in_sizes[1];   // P*4
    const int P         = in_sizes[2];   // pillar count

    float* out            = (float*)d_out;
    vfloat4* out_pillars4 = (vfloat4*)out;
    float* out_coors      = out + n_pillars;
    float* out_np         = out_coors + n_coors;
    float* canvas         = out_np + P;
    long canvas_elems     = (long)out_size - n_pillars - n_coors - P;  // bs*3*y_l*x_l
    long n4               = canvas_elems >> 2;  // canvas start is 16B-aligned here

    // Single cooperative launch: 1024 blocks x 256 threads (4 blocks/CU on
    // 256 CUs -- co-resident at this register footprint; harness fills reach
    // 7 TB/s at ~3 waves/CU, so this occupancy saturates HBM).
    dim3 grid(1024), block(256);
    void* args[] = {
        (void*)&pillars4, (void*)&coors4, (void*)&npoints,
        (void*)&xlp, (void*)&ylp,
        (void*)&out_pillars4, (void*)&out_coors, (void*)&out_np,
        (void*)&canvas, (void*)&n4, (void*)&P
    };
    hipLaunchCooperativeKernel((const void*)pillar_coop, grid, block, args, 0, stream);
}

// Round 15
// 72.448 us; speedup vs baseline: 2.2320x; 2.2320x over previous
//
#include <hip/hip_runtime.h>

// PillarLayer: fused copy + per-pillar xyz center-of-mass + BEV canvas scatter.
//
// FINAL (R15 = R13, the best measured config, 72.06us):
//   K1 canvas_zero: grid-stride float4 zero of the 20.6MB canvas (cacheable
//      -> L3-resident lines absorb the scatter RMW).
//   K2 pillar_fused: 16 lanes/pillar, 2 NT float4 loads per lane (read-once
//      stream stays out of L3), cacheable writeback stores, 4-step butterfly
//      (12 ds_swizzle per 2KB wave), direct 3-plane scatter via lanes 0-2.
//
// Ladder: naive-fill 89.1 -> own zero kernel 79.5 -> NT loads 76.7 ->
// 16-lane/2xfloat4 DS-lean reduce 72.1us. Falsified: gather structure (x2),
// 4-lane clusters, DPP reduce, NT scatter stores, batched-MLP, store-policy
// A/B, cooperative fusion (161us). Effective BW ~5.8 TB/s vs 6.29 TB/s
// measured copy ceiling (m13) -- ~90% of practical mixed-stream roofline.
//
// Inputs: d_in[0] pillars f32 (P,32,4); d_in[1] coors int32 (P,4) [b,x,y,z];
//         d_in[2] npoints int32 (P); d_in[3] bs; d_in[4] x_l; d_in[5] y_l.
// Output (concat f32): pillars copy | coors as f32 | npoints as f32 |
//         canvas (bs,3,y_l,x_l) with canvas[b][c][y][x] = center_c or 0.

typedef float vfloat4 __attribute__((ext_vector_type(4)));

__global__ __launch_bounds__(256) void canvas_zero(float4* __restrict__ dst, long n4) {
    long i = (long)blockIdx.x * blockDim.x + threadIdx.x;
    const long stride = (long)gridDim.x * blockDim.x;
    const float4 z = make_float4(0.f, 0.f, 0.f, 0.f);
    for (; i < n4; i += stride) dst[i] = z;   // cacheable: L3-resident for scatter
}

__global__ __launch_bounds__(256) void pillar_fused(
    const vfloat4* __restrict__ pillars4,  // P*32 (one float4 per point)
    const int4* __restrict__ coors4,       // P [b,x,y,z]
    const int* __restrict__ npoints,       // P
    const int* __restrict__ xlp,           // scalar x_l
    const int* __restrict__ ylp,           // scalar y_l
    vfloat4* __restrict__ out_pillars4,    // P*32
    float4* __restrict__ out_coors4,       // P
    float* __restrict__ out_np,            // P
    float* __restrict__ canvas,            // bs*3*y_l*x_l
    int P)
{
    const int tid  = threadIdx.x;
    const int g    = tid >> 4;                 // pillar group within block (0..15)
    const int r    = tid & 15;                 // lane within pillar
    const int p    = blockIdx.x * 16 + g;      // pillar id (16 pillars/block)
    if (p >= P) return;

    const long b0 = (long)p * 32;              // pillar's first float4

    // Loads NT (read-once, keep L3 for the zeroed canvas); per instruction a
    // wave covers 4 x 256B full-line segments.
    const vfloat4 v0 = __builtin_nontemporal_load(&pillars4[b0 + r]);
    const vfloat4 v1 = __builtin_nontemporal_load(&pillars4[b0 + r + 16]);
    // Stores CACHEABLE (writeback merges full lines at HBM).
    out_pillars4[b0 + r]      = v0;
    out_pillars4[b0 + r + 16] = v1;

    // Local pair-add then 4-step butterfly within the 16-lane group
    // (xor masks < 16 stay inside the group on wave64): 12 DS ops/wave/2KB.
    float sx = v0.x + v1.x, sy = v0.y + v1.y, sz = v0.z + v1.z;
    #pragma unroll
    for (int m = 8; m >= 1; m >>= 1) {
        sx += __shfl_xor(sx, m);
        sy += __shfl_xor(sy, m);
        sz += __shfl_xor(sz, m);
    }

    if (r < 3) {
        // 12 active lanes/wave; coors4[p]: 4 distinct 16B addrs (broadcast per group).
        const int4 c   = coors4[p];
        const int npts = npoints[p];
        const float s  = (r == 0) ? sx : (r == 1) ? sy : sz;
        const float val = s / (float)npts;

        const int x_l = *xlp;
        const int y_l = *ylp;
        const long cs   = (long)y_l * (long)x_l;           // plane stride
        const long base = (long)c.x * 3l * cs + (long)c.z * (long)x_l + (long)c.y;
        canvas[base + (long)r * cs] = val;                 // plane r via lane r

        if (r == 0) {
            out_coors4[p] = make_float4((float)c.x, (float)c.y, (float)c.z, (float)c.w);
            out_np[p]     = (float)npts;
        }
    }
}

extern "C" void kernel_launch(void* const* d_in, const int* in_sizes, int n_in,
                              void* d_out, int out_size, void* d_ws, size_t ws_size,
                              hipStream_t stream) {
    const vfloat4* pillars4 = (const vfloat4*)d_in[0];
    const int4* coors4      = (const int4*)d_in[1];
    const int* npoints      = (const int*)d_in[2];
    const int* xlp = (const int*)d_in[4];
    const int* ylp = (const int*)d_in[5];

    const int n_pillars = in_sizes[0];   // P*128
    const int n_coors   = in_sizes[1];   // P*4
    const int P         = in_sizes[2];   // pillar count

    float* out            = (float*)d_out;
    vfloat4* out_pillars4 = (vfloat4*)out;
    float* out_coors      = out + n_pillars;
    float* out_np         = out_coors + n_coors;
    float* canvas         = out_np + P;
    const long canvas_elems = (long)out_size - n_pillars - n_coors - P;  // bs*3*y_l*x_l

    // K1: zero canvas (cacheable -> L3 resident for the scatter RMW).
    const long n4 = canvas_elems >> 2;   // canvas start is 16B-aligned here
    int zblocks = (int)((n4 + 511) / 512);
    if (zblocks > 2048) zblocks = 2048;
    canvas_zero<<<zblocks, 256, 0, stream>>>((float4*)canvas, n4);

    // K2: fused copy + reduce + scatter. 16 pillars per 256-thread block.
    const int blocks = (P + 15) / 16;
    pillar_fused<<<blocks, 256, 0, stream>>>(
        pillars4, coors4, npoints, xlp, ylp,
        out_pillars4, (float4*)out_coors, out_np, canvas, P);
}